// Round 3
// baseline (634.512 us; speedup 1.0000x reference)
//
#include <hip/hip_runtime.h>
#include <cmath>

// Problem constants
#define NN  5
#define BB  4
#define CCH 256
#define HWD 1024
#define THRESH_V 0.3f
#define EPS_V 1e-12f

// Tiling: block = 6 waves; wave s<5 computes stream A[i]@x[s], wave 5 computes
// W2[i]@x[i]. Each wave: 32 rows (channels) x 64 cols (hw), frag 8x4 per lane
// (32 accs). K chunked by 16; wave-private LDS staging -> ZERO barriers in the
// main loop (each wave reads only the LDS it wrote).
#define CT 32          // channel rows per block
#define WT 64          // hw cols per block
#define KC 16          // k chunk
#define APAD 36        // A row stride (floats): 144B, 16B-aligned
#define NCHUNK (CCH / KC)

// LDS layout (floats):
//   main loop: Xw[wave][KC*WT=1024] @ 0      (6*1024 = 6144)
//              Aw[wave][KC*APAD=576] @ 6144  (6*576  = 3456)  total 9600
//   epilogue:  Es[6][CT][ESP=68] @ 0 overlay (6*2176 = 13056) -- after barrier
#define ESP 68
#define SMEM_FLOATS 13056

__global__ __launch_bounds__(384, 4)
void fub_main(const float* __restrict__ x, const float* __restrict__ wmat,
              const float* __restrict__ conv_w, const float* __restrict__ conv_b,
              float* __restrict__ out)
{
    __shared__ __align__(16) float smem[SMEM_FLOATS];

    const int tid  = threadIdx.x;
    const int wv   = tid >> 6;         // 0..5 stream id
    const int lane = tid & 63;

    int bid = blockIdx.x;
    const int hwt = bid & 15; bid >>= 4;    // 16 hw tiles of 64
    const int b   = bid & 3;  bid >>= 2;
    const int ct  = bid & 7;  bid >>= 3;    // 8 channel tiles of 32
    const int i   = bid;                    // 0..4

    const int c0  = ct * CT;
    const int hw0 = hwt * WT;

    float* Xw = smem + wv * (KC * WT);          // this wave's x tile
    float* Aw = smem + 6144 + wv * (KC * APAD); // this wave's weight tile

    const int lr = (lane >> 4) << 3;   // row base 0,8,16,24
    const int lc = (lane & 15) << 2;   // col base 0..60

    const int jx = (wv < 5) ? wv : i;  // which x[] this wave multiplies

    // global bases
    const float* xg = x + (size_t)((jx * BB + b) * CCH) * HWD + hw0; // + k*HWD
    // x staging addressing: per it, load k = (lane>>4) + it*4, col = (lane&15)*4
    const int xk  = lane >> 4;          // 0..3
    const int xc4 = (lane & 15) << 2;
    // weight staging addressing: row c = lane>>1, k-quad = (lane&1)*8
    const int acr = lane >> 1;          // 0..31
    const int akq = (lane & 1) << 3;    // 0 or 8
    const float* wg = conv_w + (size_t)(i * CCH + c0 + acr) * (2 * CCH) + akq;

    float acc[8][4];
#pragma unroll
    for (int r = 0; r < 8; ++r)
#pragma unroll
        for (int c = 0; c < 4; ++c) acc[r][c] = 0.0f;

    // prefetch registers (single buffer: written to LDS, then reloaded)
    float4 xr[4];
    float4 w1a, w1b, w2a, w2b;

    // ---- prologue: issue chunk 0 loads ----
#pragma unroll
    for (int it = 0; it < 4; ++it)
        xr[it] = *(const float4*)(xg + (size_t)(xk + it * 4) * HWD + xc4);
    w1a = *(const float4*)(wg);
    w1b = *(const float4*)(wg + 4);
    w2a = *(const float4*)(wg + CCH);
    w2b = *(const float4*)(wg + CCH + 4);

    for (int ch = 0; ch < NCHUNK; ++ch) {
        // ---- write staged chunk to this wave's private LDS ----
#pragma unroll
        for (int it = 0; it < 4; ++it)
            *(float4*)(Xw + (xk + it * 4) * WT + xc4) = xr[it];

        float av[8];
        if (wv != 5) {
            av[0] = w1a.x + w2a.x; av[1] = w1a.y + w2a.y;
            av[2] = w1a.z + w2a.z; av[3] = w1a.w + w2a.w;
            av[4] = w1b.x + w2b.x; av[5] = w1b.y + w2b.y;
            av[6] = w1b.z + w2b.z; av[7] = w1b.w + w2b.w;
        } else {
            av[0] = w2a.x; av[1] = w2a.y; av[2] = w2a.z; av[3] = w2a.w;
            av[4] = w2b.x; av[5] = w2b.y; av[6] = w2b.z; av[7] = w2b.w;
        }
#pragma unroll
        for (int t = 0; t < 8; ++t)
            Aw[(akq + t) * APAD + acr] = av[t];

        // ---- issue next chunk's global loads (hidden behind compute) ----
        if (ch + 1 < NCHUNK) {
            const int k0n = (ch + 1) * KC;
#pragma unroll
            for (int it = 0; it < 4; ++it)
                xr[it] = *(const float4*)(xg + (size_t)(k0n + xk + it * 4) * HWD + xc4);
            const float* wgn = wg + k0n;
            w1a = *(const float4*)(wgn);
            w1b = *(const float4*)(wgn + 4);
            w2a = *(const float4*)(wgn + CCH);
            w2b = *(const float4*)(wgn + CCH + 4);
        }

        // ---- compute: 16 k-steps, wave-private LDS reads, no barrier ----
#pragma unroll
        for (int k = 0; k < KC; ++k) {
            const float4 a0 = *(const float4*)(Aw + k * APAD + lr);
            const float4 a1 = *(const float4*)(Aw + k * APAD + lr + 4);
            const float4 xv = *(const float4*)(Xw + k * WT + lc);
            const float ar[8] = {a0.x, a0.y, a0.z, a0.w, a1.x, a1.y, a1.z, a1.w};
            const float xc[4] = {xv.x, xv.y, xv.z, xv.w};
#pragma unroll
            for (int r = 0; r < 8; ++r)
#pragma unroll
                for (int c = 0; c < 4; ++c)
                    acc[r][c] = fmaf(ar[r], xc[c], acc[r][c]);
        }
    }

    // ---- exchange streams through LDS (overlay; needs barriers) ----
    __syncthreads();   // all waves done with private regions
    float* Es = smem;  // [6][CT][ESP]
#pragma unroll
    for (int r = 0; r < 8; ++r)
        *(float4*)(Es + wv * (CT * ESP) + (lr + r) * ESP + lc) =
            make_float4(acc[r][0], acc[r][1], acc[r][2], acc[r][3]);
    __syncthreads();

    // ---- fused epilogue: threads 0..255, 8 elements (2 float4) each ----
    if (tid < 256) {
        const int row  = tid >> 3;          // 0..31
        const int col8 = (tid & 7) << 3;    // 0,8,...,56
        const int c    = c0 + row;
        const float bias = conv_b[i * CCH + c];

        float wrow[NN];
#pragma unroll
        for (int j = 0; j < NN; ++j) wrow[j] = wmat[i * NN + j];

        const float4 T0 = *(const float4*)(Es + 5 * (CT * ESP) + row * ESP + col8);
        const float4 T1 = *(const float4*)(Es + 5 * (CT * ESP) + row * ESP + col8 + 4);
        const float Tv[8] = {T0.x, T0.y, T0.z, T0.w, T1.x, T1.y, T1.z, T1.w};

        float num[8] = {0,0,0,0,0,0,0,0};
        float sq [8] = {0,0,0,0,0,0,0,0};
#pragma unroll
        for (int j = 0; j < NN; ++j) {
            const float4 s0 = *(const float4*)(Es + j * (CT * ESP) + row * ESP + col8);
            const float4 s1 = *(const float4*)(Es + j * (CT * ESP) + row * ESP + col8 + 4);
            const float* xp = x + (size_t)((j * BB + b) * CCH + c) * HWD + hw0 + col8;
            const float4 xa = *(const float4*)(xp);
            const float4 xb = *(const float4*)(xp + 4);
            const float sv[8] = {s0.x, s0.y, s0.z, s0.w, s1.x, s1.y, s1.z, s1.w};
            const float xv[8] = {xa.x, xa.y, xa.z, xa.w, xb.x, xb.y, xb.z, xb.w};
            const float wj = wrow[j];
#pragma unroll
            for (int cc = 0; cc < 8; ++cc) {
                const float dist = xv[cc] - (sv[cc] + Tv[cc] + bias);
                const float z    = dist * wj;
                float e = 1.0f / (1.0f + __expf(-z));
                e = (e > THRESH_V) ? e : 0.0f;
                sq[cc]  = fmaf(e, e, sq[cc]);
                num[cc] = fmaf(e, xv[cc], num[cc]);
            }
        }
        float res[8];
#pragma unroll
        for (int cc = 0; cc < 8; ++cc)
            res[cc] = num[cc] / fmaxf(sqrtf(sq[cc]), EPS_V);

        float* op = out + (size_t)((i * BB + b) * CCH + c) * HWD + hw0 + col8;
        *(float4*)(op)     = make_float4(res[0], res[1], res[2], res[3]);
        *(float4*)(op + 4) = make_float4(res[4], res[5], res[6], res[7]);
    }
}

extern "C" void kernel_launch(void* const* d_in, const int* in_sizes, int n_in,
                              void* d_out, int out_size, void* d_ws, size_t ws_size,
                              hipStream_t stream) {
    const float* x      = (const float*)d_in[0];
    const float* w      = (const float*)d_in[1];
    const float* conv_w = (const float*)d_in[2];
    const float* conv_b = (const float*)d_in[3];
    float* out = (float*)d_out;

    // grid: i(5) * ct(8) * b(4) * hwt(16) = 2560 blocks of 384 threads
    dim3 grid(2560);
    dim3 block(384);
    fub_main<<<grid, block, 0, stream>>>(x, w, conv_w, conv_b, out);
}

// Round 4
// 403.736 us; speedup vs baseline: 1.5716x; 1.5716x over previous
//
#include <hip/hip_runtime.h>
#include <cmath>

// Problem constants (from reference)
#define NN  5      // N_NODES
#define BB  4      // batch
#define CCH 256    // channels
#define HWD 1024   // H*W
#define THRESH_V 0.3f
#define EPS_V 1e-12f

// Tile config: block = 384 threads = 6 waves; wave w<5 computes stream
// A[i]@x[w]; wave 5 computes W2[i]@x[i]. Each wave owns a 32x32 output tile
// (4x4 frag per lane -> 16 accumulators, no spill). R4: software-pipelined
// staging — chunk ch+1's global loads are issued right after the post-staging
// barrier so their latency overlaps chunk ch's 1024-cycle compute phase.
#define CT 32      // channel rows per block
#define WT 32      // hw cols per block
#define KC 32      // k chunk
#define NCHUNK (CCH / KC)
#define APAD 36    // padded LDS row stride (floats) for A/W2
#define SPAD 36    // Es col stride (floats)

// smem layout (floats):
//   staging phase: Xs[5][32][32] @0 (5120) | As[32][36] @5120 (1152) | W2s @6272 (1152)
//   epilogue:      Es[6][32][36] @0 (6912)   -- overlaid
#define SMEM_FLOATS 7424

__global__ __launch_bounds__(384, 4)
void fub_main(const float* __restrict__ x, const float* __restrict__ wmat,
              const float* __restrict__ conv_w, const float* __restrict__ conv_b,
              float* __restrict__ out)
{
    __shared__ __align__(16) float smem[SMEM_FLOATS];
    float* Xs  = smem;          // [5][KC][WT]
    float* As  = smem + 5120;   // [KC][APAD]
    float* W2s = smem + 6272;   // [KC][APAD]
    float* Es  = smem;          // [6][CT][SPAD] overlay (epilogue only)

    const int tid  = threadIdx.x;
    const int wv   = tid >> 6;        // 0..5 : stream id
    const int lane = tid & 63;

    int bid = blockIdx.x;
    const int hwt = bid & 31; bid >>= 5;   // 32 hw tiles
    const int b   = bid & 3;  bid >>= 2;   // 4 batches
    const int ct  = bid & 7;  bid >>= 3;   // 8 channel tiles
    const int i   = bid;                   // 0..4

    const int c0  = ct * CT;
    const int hw0 = hwt * WT;

    const int lr = (lane >> 3) << 2;  // frag row base 0,4,...,28
    const int lc = (lane & 7)  << 2;  // frag col base 0,4,...,28

    // stream w<5 multiplies A by x[w]; stream 5 multiplies W2 by x[i]
    const int jx = (wv < 5) ? wv : i;
    const float* M  = (wv == 5) ? W2s : As;
    const float* Mb = M + lr;
    const float* Xb = Xs + jx * (KC * WT) + lc;

    float acc[4][4];
#pragma unroll
    for (int r = 0; r < 4; ++r)
#pragma unroll
        for (int c = 0; c < 4; ++c) acc[r][c] = 0.0f;

    // ---- prefetch state ----
    const bool xloader = (tid < 320);
    float4 pfa[4];   // x-loader: 4 x float4   | weight-loader: W1 quads
    float4 pfb[4];   //                         | weight-loader: W2 quads

    // per-role staging geometry (chunk-invariant parts)
    // x-loader (threads 0..319): 4 iterations, t = tid + it*320
    //   j = t>>8, kk = (t&255)>>3, p4 = (t&7)<<2
    // weight-loader (threads 320..383): 4 iterations, t = (tid-320) + it*64
    //   r = t>>3, kq = (t&7)<<2

    // ---- issue chunk 0 loads ----
    {
        const int k0 = 0;
        if (xloader) {
#pragma unroll
            for (int it = 0; it < 4; ++it) {
                const int t   = tid + it * 320;
                const int j   = t >> 8;
                const int kk  = (t & 255) >> 3;
                const int p4  = (t & 7) << 2;
                pfa[it] = *(const float4*)(
                    x + (size_t)((j * BB + b) * CCH + k0 + kk) * HWD + hw0 + p4);
            }
        } else {
            const int u = tid - 320;
#pragma unroll
            for (int it = 0; it < 4; ++it) {
                const int t  = u + (it << 6);
                const int r  = t >> 3;
                const int kq = (t & 7) << 2;
                const float* base =
                    conv_w + (size_t)(i * CCH + c0 + r) * (2 * CCH) + k0 + kq;
                pfa[it] = *(const float4*)(base);        // W1
                pfb[it] = *(const float4*)(base + CCH);  // W2
            }
        }
    }

    for (int ch = 0; ch < NCHUNK; ++ch) {
        if (ch) __syncthreads();   // prior compute done before LDS overwrite

        // ---- drain prefetch regs into LDS ----
        if (xloader) {
#pragma unroll
            for (int it = 0; it < 4; ++it) {
                const int t   = tid + it * 320;
                const int j   = t >> 8;
                const int kk  = (t & 255) >> 3;
                const int p4  = (t & 7) << 2;
                *(float4*)(Xs + j * (KC * WT) + kk * WT + p4) = pfa[it];
            }
        } else {
            const int u = tid - 320;
#pragma unroll
            for (int it = 0; it < 4; ++it) {
                const int t  = u + (it << 6);
                const int r  = t >> 3;
                const int kq = (t & 7) << 2;
                const float4 w1 = pfa[it];
                const float4 w2 = pfb[it];
                As [(kq + 0) * APAD + r] = w1.x + w2.x;
                As [(kq + 1) * APAD + r] = w1.y + w2.y;
                As [(kq + 2) * APAD + r] = w1.z + w2.z;
                As [(kq + 3) * APAD + r] = w1.w + w2.w;
                W2s[(kq + 0) * APAD + r] = w2.x;
                W2s[(kq + 1) * APAD + r] = w2.y;
                W2s[(kq + 2) * APAD + r] = w2.z;
                W2s[(kq + 3) * APAD + r] = w2.w;
            }
        }
        __syncthreads();

        // ---- issue chunk ch+1's global loads (latency hidden by compute) ----
        if (ch + 1 < NCHUNK) {
            const int k0 = (ch + 1) * KC;
            if (xloader) {
#pragma unroll
                for (int it = 0; it < 4; ++it) {
                    const int t   = tid + it * 320;
                    const int j   = t >> 8;
                    const int kk  = (t & 255) >> 3;
                    const int p4  = (t & 7) << 2;
                    pfa[it] = *(const float4*)(
                        x + (size_t)((j * BB + b) * CCH + k0 + kk) * HWD + hw0 + p4);
                }
            } else {
                const int u = tid - 320;
#pragma unroll
                for (int it = 0; it < 4; ++it) {
                    const int t  = u + (it << 6);
                    const int r  = t >> 3;
                    const int kq = (t & 7) << 2;
                    const float* base =
                        conv_w + (size_t)(i * CCH + c0 + r) * (2 * CCH) + k0 + kq;
                    pfa[it] = *(const float4*)(base);
                    pfb[it] = *(const float4*)(base + CCH);
                }
            }
        }

        // ---- compute: each wave does its own stream's 32x32 tile ----
#pragma unroll
        for (int kk = 0; kk < KC; ++kk) {
            const float4 a  = *(const float4*)(Mb + kk * APAD);
            const float4 xv = *(const float4*)(Xb + kk * WT);
            const float ar[4] = {a.x, a.y, a.z, a.w};
            const float xc[4] = {xv.x, xv.y, xv.z, xv.w};
#pragma unroll
            for (int r = 0; r < 4; ++r)
#pragma unroll
                for (int c = 0; c < 4; ++c)
                    acc[r][c] = fmaf(ar[r], xc[c], acc[r][c]);
        }
    }

    // ---- exchange streams through LDS (Es overlays staging buffers) ----
    __syncthreads();
#pragma unroll
    for (int r = 0; r < 4; ++r) {
        *(float4*)(Es + wv * (CT * SPAD) + (lr + r) * SPAD + lc) =
            make_float4(acc[r][0], acc[r][1], acc[r][2], acc[r][3]);
    }
    __syncthreads();

    // ---- fused epilogue: threads 0..255, 4 elements each ----
    if (tid < 256) {
        const int row = tid >> 3;           // 0..31
        const int col = (tid & 7) << 2;     // 0..28
        const int c   = c0 + row;
        const float bias = conv_b[i * CCH + c];

        float wrow[NN];
#pragma unroll
        for (int j = 0; j < NN; ++j) wrow[j] = wmat[i * NN + j];

        const float4 T = *(const float4*)(Es + 5 * (CT * SPAD) + row * SPAD + col);
        const float Tv[4] = {T.x, T.y, T.z, T.w};

        float num[4] = {0.f, 0.f, 0.f, 0.f};
        float sq [4] = {0.f, 0.f, 0.f, 0.f};
#pragma unroll
        for (int j = 0; j < NN; ++j) {
            const float4 s  = *(const float4*)(Es + j * (CT * SPAD) + row * SPAD + col);
            const float4 xj = *(const float4*)(
                x + (size_t)((j * BB + b) * CCH + c) * HWD + hw0 + col);
            const float sv[4] = {s.x, s.y, s.z, s.w};
            const float xv[4] = {xj.x, xj.y, xj.z, xj.w};
            const float wj = wrow[j];
#pragma unroll
            for (int cc = 0; cc < 4; ++cc) {
                const float dist = xv[cc] - (sv[cc] + Tv[cc] + bias);
                const float z    = dist * wj;
                float e = 1.0f / (1.0f + __expf(-z));
                e = (e > THRESH_V) ? e : 0.0f;
                sq[cc]  = fmaf(e, e, sq[cc]);
                num[cc] = fmaf(e, xv[cc], num[cc]);
            }
        }
        float res[4];
#pragma unroll
        for (int cc = 0; cc < 4; ++cc)
            res[cc] = num[cc] / fmaxf(sqrtf(sq[cc]), EPS_V);

        *(float4*)(out + (size_t)((i * BB + b) * CCH + c) * HWD + hw0 + col) =
            make_float4(res[0], res[1], res[2], res[3]);
    }
}

extern "C" void kernel_launch(void* const* d_in, const int* in_sizes, int n_in,
                              void* d_out, int out_size, void* d_ws, size_t ws_size,
                              hipStream_t stream) {
    const float* x      = (const float*)d_in[0];
    const float* w      = (const float*)d_in[1];
    const float* conv_w = (const float*)d_in[2];
    const float* conv_b = (const float*)d_in[3];
    float* out = (float*)d_out;

    // grid: i(5) * ct(8) * b(4) * hwt(32) = 5120 blocks of 384 threads
    dim3 grid(5120);
    dim3 block(384);
    fub_main<<<grid, block, 0, stream>>>(x, w, conv_w, conv_b, out);
}

// Round 5
// 383.591 us; speedup vs baseline: 1.6541x; 1.0525x over previous
//
#include <hip/hip_runtime.h>
#include <cmath>

// Problem constants (from reference)
#define NN  5      // N_NODES
#define BB  4      // batch
#define CCH 256    // channels
#define HWD 1024   // H*W
#define THRESH_V 0.3f
#define EPS_V 1e-12f

// Tile config: block = 384 threads = 6 waves; wave w<5 computes stream
// A[i]@x[w]; wave 5 computes W2[i]@x[i]. Each wave owns a 32x32 output tile
// (4x4 frag per lane -> 16 accumulators). Software-pipelined staging: chunk
// ch+1's global loads issue right after the post-staging barrier, overlapping
// chunk ch's ~1024-cycle FMA phase.
// NOTE: no __launch_bounds__ minimum — R4 showed (384,4) clamps VGPR to 64 and
// spills the prefetch registers (218 MB scratch writes). Let the allocator
// hold ~96-128 VGPR; 3 blocks/CU is plenty.
#define CT 32      // channel rows per block
#define WT 32      // hw cols per block
#define KC 32      // k chunk
#define NCHUNK (CCH / KC)
#define APAD 36    // padded LDS row stride (floats) for A/W2
#define SPAD 36    // Es col stride (floats)

// smem layout (floats):
//   staging phase: Xs[5][32][32] @0 (5120) | As[32][36] @5120 (1152) | W2s @6272 (1152)
//   epilogue:      Es[6][32][36] @0 (6912)   -- overlaid
#define SMEM_FLOATS 7424

__global__ __launch_bounds__(384)
void fub_main(const float* __restrict__ x, const float* __restrict__ wmat,
              const float* __restrict__ conv_w, const float* __restrict__ conv_b,
              float* __restrict__ out)
{
    __shared__ __align__(16) float smem[SMEM_FLOATS];
    float* Xs  = smem;          // [5][KC][WT]
    float* As  = smem + 5120;   // [KC][APAD]
    float* W2s = smem + 6272;   // [KC][APAD]
    float* Es  = smem;          // [6][CT][SPAD] overlay (epilogue only)

    const int tid  = threadIdx.x;
    const int wv   = tid >> 6;        // 0..5 : stream id
    const int lane = tid & 63;

    int bid = blockIdx.x;
    const int hwt = bid & 31; bid >>= 5;   // 32 hw tiles
    const int b   = bid & 3;  bid >>= 2;   // 4 batches
    const int ct  = bid & 7;  bid >>= 3;   // 8 channel tiles
    const int i   = bid;                   // 0..4

    const int c0  = ct * CT;
    const int hw0 = hwt * WT;

    const int lr = (lane >> 3) << 2;  // frag row base 0,4,...,28
    const int lc = (lane & 7)  << 2;  // frag col base 0,4,...,28

    // stream w<5 multiplies A by x[w]; stream 5 multiplies W2 by x[i]
    const int jx = (wv < 5) ? wv : i;
    const float* M  = (wv == 5) ? W2s : As;
    const float* Mb = M + lr;
    const float* Xb = Xs + jx * (KC * WT) + lc;

    float acc[4][4];
#pragma unroll
    for (int r = 0; r < 4; ++r)
#pragma unroll
        for (int c = 0; c < 4; ++c) acc[r][c] = 0.0f;

    // ---- prefetch state ----
    const bool xloader = (tid < 320);
    float4 pfa[4];   // x-loader: 4 x float4   | weight-loader: W1 quads
    float4 pfb[4];   //                         | weight-loader: W2 quads

    // ---- issue chunk 0 loads ----
    {
        const int k0 = 0;
        if (xloader) {
#pragma unroll
            for (int it = 0; it < 4; ++it) {
                const int t   = tid + it * 320;
                const int j   = t >> 8;
                const int kk  = (t & 255) >> 3;
                const int p4  = (t & 7) << 2;
                pfa[it] = *(const float4*)(
                    x + (size_t)((j * BB + b) * CCH + k0 + kk) * HWD + hw0 + p4);
            }
        } else {
            const int u = tid - 320;
#pragma unroll
            for (int it = 0; it < 4; ++it) {
                const int t  = u + (it << 6);
                const int r  = t >> 3;
                const int kq = (t & 7) << 2;
                const float* base =
                    conv_w + (size_t)(i * CCH + c0 + r) * (2 * CCH) + k0 + kq;
                pfa[it] = *(const float4*)(base);        // W1
                pfb[it] = *(const float4*)(base + CCH);  // W2
            }
        }
    }

    for (int ch = 0; ch < NCHUNK; ++ch) {
        if (ch) __syncthreads();   // prior compute done before LDS overwrite

        // ---- drain prefetch regs into LDS ----
        if (xloader) {
#pragma unroll
            for (int it = 0; it < 4; ++it) {
                const int t   = tid + it * 320;
                const int j   = t >> 8;
                const int kk  = (t & 255) >> 3;
                const int p4  = (t & 7) << 2;
                *(float4*)(Xs + j * (KC * WT) + kk * WT + p4) = pfa[it];
            }
        } else {
            const int u = tid - 320;
#pragma unroll
            for (int it = 0; it < 4; ++it) {
                const int t  = u + (it << 6);
                const int r  = t >> 3;
                const int kq = (t & 7) << 2;
                const float4 w1 = pfa[it];
                const float4 w2 = pfb[it];
                As [(kq + 0) * APAD + r] = w1.x + w2.x;
                As [(kq + 1) * APAD + r] = w1.y + w2.y;
                As [(kq + 2) * APAD + r] = w1.z + w2.z;
                As [(kq + 3) * APAD + r] = w1.w + w2.w;
                W2s[(kq + 0) * APAD + r] = w2.x;
                W2s[(kq + 1) * APAD + r] = w2.y;
                W2s[(kq + 2) * APAD + r] = w2.z;
                W2s[(kq + 3) * APAD + r] = w2.w;
            }
        }
        __syncthreads();

        // ---- issue chunk ch+1's global loads (latency hidden by compute) ----
        if (ch + 1 < NCHUNK) {
            const int k0 = (ch + 1) * KC;
            if (xloader) {
#pragma unroll
                for (int it = 0; it < 4; ++it) {
                    const int t   = tid + it * 320;
                    const int j   = t >> 8;
                    const int kk  = (t & 255) >> 3;
                    const int p4  = (t & 7) << 2;
                    pfa[it] = *(const float4*)(
                        x + (size_t)((j * BB + b) * CCH + k0 + kk) * HWD + hw0 + p4);
                }
            } else {
                const int u = tid - 320;
#pragma unroll
                for (int it = 0; it < 4; ++it) {
                    const int t  = u + (it << 6);
                    const int r  = t >> 3;
                    const int kq = (t & 7) << 2;
                    const float* base =
                        conv_w + (size_t)(i * CCH + c0 + r) * (2 * CCH) + k0 + kq;
                    pfa[it] = *(const float4*)(base);
                    pfb[it] = *(const float4*)(base + CCH);
                }
            }
        }

        // ---- compute: each wave does its own stream's 32x32 tile ----
#pragma unroll
        for (int kk = 0; kk < KC; ++kk) {
            const float4 a  = *(const float4*)(Mb + kk * APAD);
            const float4 xv = *(const float4*)(Xb + kk * WT);
            const float ar[4] = {a.x, a.y, a.z, a.w};
            const float xc[4] = {xv.x, xv.y, xv.z, xv.w};
#pragma unroll
            for (int r = 0; r < 4; ++r)
#pragma unroll
                for (int c = 0; c < 4; ++c)
                    acc[r][c] = fmaf(ar[r], xc[c], acc[r][c]);
        }
    }

    // ---- exchange streams through LDS (Es overlays staging buffers) ----
    __syncthreads();
#pragma unroll
    for (int r = 0; r < 4; ++r) {
        *(float4*)(Es + wv * (CT * SPAD) + (lr + r) * SPAD + lc) =
            make_float4(acc[r][0], acc[r][1], acc[r][2], acc[r][3]);
    }
    __syncthreads();

    // ---- fused epilogue: threads 0..255, 4 elements each ----
    if (tid < 256) {
        const int row = tid >> 3;           // 0..31
        const int col = (tid & 7) << 2;     // 0..28
        const int c   = c0 + row;
        const float bias = conv_b[i * CCH + c];

        float wrow[NN];
#pragma unroll
        for (int j = 0; j < NN; ++j) wrow[j] = wmat[i * NN + j];

        const float4 T = *(const float4*)(Es + 5 * (CT * SPAD) + row * SPAD + col);
        const float Tv[4] = {T.x, T.y, T.z, T.w};

        float num[4] = {0.f, 0.f, 0.f, 0.f};
        float sq [4] = {0.f, 0.f, 0.f, 0.f};
#pragma unroll
        for (int j = 0; j < NN; ++j) {
            const float4 s  = *(const float4*)(Es + j * (CT * SPAD) + row * SPAD + col);
            const float4 xj = *(const float4*)(
                x + (size_t)((j * BB + b) * CCH + c) * HWD + hw0 + col);
            const float sv[4] = {s.x, s.y, s.z, s.w};
            const float xv[4] = {xj.x, xj.y, xj.z, xj.w};
            const float wj = wrow[j];
#pragma unroll
            for (int cc = 0; cc < 4; ++cc) {
                const float dist = xv[cc] - (sv[cc] + Tv[cc] + bias);
                const float z    = dist * wj;
                float e = 1.0f / (1.0f + __expf(-z));
                e = (e > THRESH_V) ? e : 0.0f;
                sq[cc]  = fmaf(e, e, sq[cc]);
                num[cc] = fmaf(e, xv[cc], num[cc]);
            }
        }
        float res[4];
#pragma unroll
        for (int cc = 0; cc < 4; ++cc)
            res[cc] = num[cc] / fmaxf(sqrtf(sq[cc]), EPS_V);

        *(float4*)(out + (size_t)((i * BB + b) * CCH + c) * HWD + hw0 + col) =
            make_float4(res[0], res[1], res[2], res[3]);
    }
}

extern "C" void kernel_launch(void* const* d_in, const int* in_sizes, int n_in,
                              void* d_out, int out_size, void* d_ws, size_t ws_size,
                              hipStream_t stream) {
    const float* x      = (const float*)d_in[0];
    const float* w      = (const float*)d_in[1];
    const float* conv_w = (const float*)d_in[2];
    const float* conv_b = (const float*)d_in[3];
    float* out = (float*)d_out;

    // grid: i(5) * ct(8) * b(4) * hwt(32) = 5120 blocks of 384 threads
    dim3 grid(5120);
    dim3 block(384);
    fub_main<<<grid, block, 0, stream>>>(x, w, conv_w, conv_b, out);
}